// Round 1
// baseline (122.144 us; speedup 1.0000x reference)
//
#include <hip/hip_runtime.h>

#define F 32

// ---------------------------------------------------------------------------
// Kernel 1: y = x @ W   (N x 32) @ (32 x 32), fp32 vector ALU (no fp32 MFMA on CDNA4)
// One 32-lane group per node row; lane f holds x[n][f], broadcasts via shfl.
// ---------------------------------------------------------------------------
__global__ void xw_kernel(const float* __restrict__ x, const float* __restrict__ w,
                          float* __restrict__ y, int n_nodes) {
    __shared__ float wld[F * F];
    for (int i = threadIdx.x; i < F * F; i += blockDim.x) wld[i] = w[i];
    __syncthreads();

    int gid = blockIdx.x * blockDim.x + threadIdx.x;
    int n = gid >> 5;
    int f = gid & 31;
    if (n >= n_nodes) return;

    float xv = x[(size_t)n * F + f];
    float acc = 0.f;
#pragma unroll
    for (int k = 0; k < F; ++k) {
        float xk = __shfl(xv, k, 32);          // broadcast x[n][k] within 32-lane group
        acc += xk * wld[k * F + f];            // lanes f=0..31 -> banks 0..31, conflict-free
    }
    y[(size_t)n * F + f] = acc;
}

// ---------------------------------------------------------------------------
// Kernel 2: build CSR row_ptr from sorted COO rows.
// row_ptr[r] = first edge index e with rows[e] >= r;  row_ptr[N] = E.
// One thread per edge (plus one tail thread e == n_edges).
// ---------------------------------------------------------------------------
__global__ void row_ptr_kernel(const int* __restrict__ rows, int* __restrict__ row_ptr,
                               int n_edges, int n_nodes) {
    int e = blockIdx.x * blockDim.x + threadIdx.x;
    if (e > n_edges) return;
    int prev = (e == 0) ? -1 : rows[e - 1];
    int cur  = (e == n_edges) ? n_nodes : rows[e];
    for (int r = prev + 1; r <= cur; ++r) {
        row_ptr[r] = e;
    }
}

// ---------------------------------------------------------------------------
// Kernel 3: out[n][f] = sum_{e in [row_ptr[n], row_ptr[n+1])} y[cols[e]][f] * vals[e]
// One 32-lane group per node. cols/vals reads are uniform within the group
// (broadcast); y row reads are 128B coalesced gathers (mostly L2/L3 hits,
// y working set = 12.8 MB). out written exactly once -> no atomics, no memset.
// ---------------------------------------------------------------------------
__global__ void spmm_kernel(const float* __restrict__ y, const int* __restrict__ cols,
                            const float* __restrict__ vals, const int* __restrict__ row_ptr,
                            float* __restrict__ out, int n_nodes) {
    int gid = blockIdx.x * blockDim.x + threadIdx.x;
    int n = gid >> 5;
    int f = gid & 31;
    if (n >= n_nodes) return;

    int e0 = row_ptr[n];
    int e1 = row_ptr[n + 1];
    float acc = 0.f;
    for (int e = e0; e < e1; ++e) {
        int   c = cols[e];
        float v = vals[e];
        acc += y[(size_t)c * F + f] * v;
    }
    out[(size_t)n * F + f] = acc;
}

// ---------------------------------------------------------------------------
extern "C" void kernel_launch(void* const* d_in, const int* in_sizes, int n_in,
                              void* d_out, int out_size, void* d_ws, size_t ws_size,
                              hipStream_t stream) {
    const float* x    = (const float*)d_in[0];
    const int*   rows = (const int*)d_in[1];
    const int*   cols = (const int*)d_in[2];
    const float* vals = (const float*)d_in[3];
    const float* w    = (const float*)d_in[4];
    float*       out  = (float*)d_out;

    int n_nodes = in_sizes[0] / F;   // 100000
    int n_edges = in_sizes[1];       // 1600000

    // workspace layout: y [n_nodes*F floats] | row_ptr [n_nodes+1 ints]
    float* y       = (float*)d_ws;
    int*   row_ptr = (int*)((char*)d_ws + (size_t)n_nodes * F * sizeof(float));

    {
        int total = n_nodes * F;
        int grid = (total + 255) / 256;
        xw_kernel<<<grid, 256, 0, stream>>>(x, w, y, n_nodes);
    }
    {
        int grid = (n_edges + 1 + 255) / 256;
        row_ptr_kernel<<<grid, 256, 0, stream>>>(rows, row_ptr, n_edges, n_nodes);
    }
    {
        int total = n_nodes * F;
        int grid = (total + 255) / 256;
        spmm_kernel<<<grid, 256, 0, stream>>>(y, cols, vals, row_ptr, out, n_nodes);
    }
}

// Round 2
// 67.747 us; speedup vs baseline: 1.8029x; 1.8029x over previous
//
#include <hip/hip_runtime.h>

#define F 32

// ---------------------------------------------------------------------------
// Prep kernel (fused): blocks [0, grid_xw) compute y = x @ W;
// blocks [grid_xw, grid_xw+grid_rp) build CSR row_ptr from sorted COO rows.
// Fusing saves one kernel-launch of overhead; the two parts touch disjoint
// data (y vs row_ptr) and spmm consumes both after this kernel completes.
// ---------------------------------------------------------------------------
__global__ void prep_kernel(const float* __restrict__ x, const float* __restrict__ w,
                            float* __restrict__ y,
                            const int* __restrict__ rows, int* __restrict__ row_ptr,
                            int n_nodes, int n_edges, int grid_xw) {
    if ((int)blockIdx.x < grid_xw) {
        // ---- y = x @ W : one 32-lane group per node row, lane f = out feature
        __shared__ float wld[F * F];
        for (int i = threadIdx.x; i < F * F; i += blockDim.x) wld[i] = w[i];
        __syncthreads();

        int gid = blockIdx.x * blockDim.x + threadIdx.x;
        int n = gid >> 5;
        int f = gid & 31;
        if (n >= n_nodes) return;

        float xv = x[(size_t)n * F + f];
        float acc = 0.f;
#pragma unroll
        for (int k = 0; k < F; ++k) {
            float xk = __shfl(xv, k, 32);      // broadcast x[n][k] within 32-lane group
            acc += xk * wld[k * F + f];        // banks 0..31, conflict-free
        }
        y[(size_t)n * F + f] = acc;
    } else {
        // ---- row_ptr[r] = first edge e with rows[e] >= r; row_ptr[N] = E
        int e = (blockIdx.x - grid_xw) * blockDim.x + threadIdx.x;
        if (e > n_edges) return;
        int prev = (e == 0) ? -1 : rows[e - 1];
        int cur  = (e == n_edges) ? n_nodes : rows[e];
        for (int r = prev + 1; r <= cur; ++r) row_ptr[r] = e;
    }
}

// ---------------------------------------------------------------------------
// SpMM: out[n][f] = sum_e y[cols[e]][f] * vals[e] over e in [row_ptr[n], row_ptr[n+1])
// One 32-lane group per node, lane = feature.
// v2: latency-bound fix (R1 counters: VALUBusy 14%, HBM 13% -> neither pipe busy).
//  - edge metadata loaded COALESCED: lane f reads cols/vals[e0+f] for a 32-edge
//    batch (1 coalesced load vs 32 uniform loads), then __shfl-broadcast.
//  - 8-way unrolled gather loop: 8 independent y-row loads in flight per group
//    instead of a 1-deep dependent chain.
// ---------------------------------------------------------------------------
__global__ void spmm_kernel(const float* __restrict__ y, const int* __restrict__ cols,
                            const float* __restrict__ vals, const int* __restrict__ row_ptr,
                            float* __restrict__ out, int n_nodes) {
    int gid = blockIdx.x * blockDim.x + threadIdx.x;
    int n = gid >> 5;
    int f = gid & 31;
    if (n >= n_nodes) return;

    int e0 = row_ptr[n];
    int e1 = row_ptr[n + 1];
    float acc = 0.f;

    for (int base = e0; base < e1; base += 32) {
        int idx = base + f;
        bool valid = idx < e1;
        int   cB = valid ? cols[idx] : 0;      // coalesced 32-edge batch load
        float vB = valid ? vals[idx] : 0.f;
        int cnt = min(32, e1 - base);

        int j = 0;
        for (; j + 8 <= cnt; j += 8) {
            int   c0 = __shfl(cB, j + 0, 32); float v0 = __shfl(vB, j + 0, 32);
            int   c1 = __shfl(cB, j + 1, 32); float v1 = __shfl(vB, j + 1, 32);
            int   c2 = __shfl(cB, j + 2, 32); float v2 = __shfl(vB, j + 2, 32);
            int   c3 = __shfl(cB, j + 3, 32); float v3 = __shfl(vB, j + 3, 32);
            int   c4 = __shfl(cB, j + 4, 32); float v4 = __shfl(vB, j + 4, 32);
            int   c5 = __shfl(cB, j + 5, 32); float v5 = __shfl(vB, j + 5, 32);
            int   c6 = __shfl(cB, j + 6, 32); float v6 = __shfl(vB, j + 6, 32);
            int   c7 = __shfl(cB, j + 7, 32); float v7 = __shfl(vB, j + 7, 32);
            // 8 independent gathers -> 8 outstanding loads
            float p0 = y[(size_t)c0 * F + f];
            float p1 = y[(size_t)c1 * F + f];
            float p2 = y[(size_t)c2 * F + f];
            float p3 = y[(size_t)c3 * F + f];
            float p4 = y[(size_t)c4 * F + f];
            float p5 = y[(size_t)c5 * F + f];
            float p6 = y[(size_t)c6 * F + f];
            float p7 = y[(size_t)c7 * F + f];
            acc += p0 * v0; acc += p1 * v1; acc += p2 * v2; acc += p3 * v3;
            acc += p4 * v4; acc += p5 * v5; acc += p6 * v6; acc += p7 * v7;
        }
        for (; j < cnt; ++j) {
            int   c = __shfl(cB, j, 32);
            float v = __shfl(vB, j, 32);
            acc += y[(size_t)c * F + f] * v;
        }
    }
    out[(size_t)n * F + f] = acc;
}

// ---------------------------------------------------------------------------
extern "C" void kernel_launch(void* const* d_in, const int* in_sizes, int n_in,
                              void* d_out, int out_size, void* d_ws, size_t ws_size,
                              hipStream_t stream) {
    const float* x    = (const float*)d_in[0];
    const int*   rows = (const int*)d_in[1];
    const int*   cols = (const int*)d_in[2];
    const float* vals = (const float*)d_in[3];
    const float* w    = (const float*)d_in[4];
    float*       out  = (float*)d_out;

    int n_nodes = in_sizes[0] / F;   // 100000
    int n_edges = in_sizes[1];       // 1600000

    // workspace layout: y [n_nodes*F floats] | row_ptr [n_nodes+1 ints]
    float* y       = (float*)d_ws;
    int*   row_ptr = (int*)((char*)d_ws + (size_t)n_nodes * F * sizeof(float));

    int grid_xw = (n_nodes * F + 255) / 256;
    int grid_rp = (n_edges + 1 + 255) / 256;
    prep_kernel<<<grid_xw + grid_rp, 256, 0, stream>>>(x, w, y, rows, row_ptr,
                                                       n_nodes, n_edges, grid_xw);

    int grid_spmm = (n_nodes * 32 + 255) / 256;
    spmm_kernel<<<grid_spmm, 256, 0, stream>>>(y, cols, vals, row_ptr, out, n_nodes);
}

// Round 3
// 59.106 us; speedup vs baseline: 2.0665x; 1.1462x over previous
//
#include <hip/hip_runtime.h>

#define F 32

// ---- bf16 helpers (manual, RNE) -------------------------------------------
__device__ __forceinline__ unsigned int f2bf_rne(float f) {
    unsigned int u = __float_as_uint(f);
    return (u + 0x7fffu + ((u >> 16) & 1u)) >> 16;          // bf16 bits in low 16
}
__device__ __forceinline__ float bf_lo(unsigned int u) {    // low bf16 -> f32
    return __uint_as_float(u << 16);
}
__device__ __forceinline__ float bf_hi(unsigned int u) {    // high bf16 -> f32
    return __uint_as_float(u & 0xffff0000u);
}

// ---------------------------------------------------------------------------
// Prep (fused): blocks [0,grid_xw): y = x @ W, stored as bf16 pairs
//   y_u[n*16 + k] = bf16(y[n][2k]) | bf16(y[n][2k+1])<<16   (6.4 MB total ->
//   fits per-XCD L2 far better than 12.8 MB fp32; halves gather traffic)
// blocks [grid_xw, ...): CSR row_ptr from sorted COO rows.
// ---------------------------------------------------------------------------
__global__ void prep_kernel(const float* __restrict__ x, const float* __restrict__ w,
                            unsigned int* __restrict__ y_u,
                            const int* __restrict__ rows, int* __restrict__ row_ptr,
                            int n_nodes, int n_edges, int grid_xw) {
    if ((int)blockIdx.x < grid_xw) {
        __shared__ float wld[F * F];
        for (int i = threadIdx.x; i < F * F; i += blockDim.x) wld[i] = w[i];
        __syncthreads();

        int gid = blockIdx.x * blockDim.x + threadIdx.x;
        int n = gid >> 5;
        int f = gid & 31;
        if (n >= n_nodes) return;

        float xv = x[(size_t)n * F + f];
        float acc = 0.f;
#pragma unroll
        for (int k = 0; k < F; ++k) {
            float xk = __shfl(xv, k, 32);        // broadcast x[n][k]
            acc += xk * wld[k * F + f];          // banks 0..31, conflict-free
        }
        // pack feature pair (2k,2k+1) into one uint; even lane stores
        unsigned int mybf = f2bf_rne(acc);
        unsigned int part = (unsigned int)__shfl((int)mybf, f ^ 1, 32);
        if ((f & 1) == 0) {
            y_u[(size_t)n * 16 + (f >> 1)] = mybf | (part << 16);
        }
    } else {
        int e = (blockIdx.x - grid_xw) * blockDim.x + threadIdx.x;
        if (e > n_edges) return;
        int prev = (e == 0) ? -1 : rows[e - 1];
        int cur  = (e == n_edges) ? n_nodes : rows[e];
        for (int r = prev + 1; r <= cur; ++r) row_ptr[r] = e;
    }
}

// ---------------------------------------------------------------------------
// SpMM: one 16-lane group per node; lane l owns feature pair (2l, 2l+1).
// Edge metadata loaded coalesced in 16-edge batches, shfl-broadcast.
// 8-deep independent gather unroll (+4/2/1 tail) for memory-level parallelism.
// Gather = 64 B per group (16 lanes x 4 B uint = bf16x2). Output float2 store
// = 128 B per group, written exactly once (no atomics, no memset needed).
// ---------------------------------------------------------------------------
__global__ void spmm_kernel(const unsigned int* __restrict__ y_u,
                            const int* __restrict__ cols,
                            const float* __restrict__ vals,
                            const int* __restrict__ row_ptr,
                            float2* __restrict__ out2, int n_nodes) {
    int gid = blockIdx.x * blockDim.x + threadIdx.x;
    int n = gid >> 4;
    int l = gid & 15;
    if (n >= n_nodes) return;

    int e0 = row_ptr[n];
    int e1 = row_ptr[n + 1];
    float accL = 0.f, accH = 0.f;

    for (int base = e0; base < e1; base += 16) {
        int idx = base + l;
        bool valid = idx < e1;
        int   cB = valid ? cols[idx] : 0;        // coalesced 16-edge batch
        float vB = valid ? vals[idx] : 0.f;
        int cnt = min(16, e1 - base);

        int j = 0;
        for (; j + 8 <= cnt; j += 8) {
            int   c0 = __shfl(cB, j + 0, 16); float v0 = __shfl(vB, j + 0, 16);
            int   c1 = __shfl(cB, j + 1, 16); float v1 = __shfl(vB, j + 1, 16);
            int   c2 = __shfl(cB, j + 2, 16); float v2 = __shfl(vB, j + 2, 16);
            int   c3 = __shfl(cB, j + 3, 16); float v3 = __shfl(vB, j + 3, 16);
            int   c4 = __shfl(cB, j + 4, 16); float v4 = __shfl(vB, j + 4, 16);
            int   c5 = __shfl(cB, j + 5, 16); float v5 = __shfl(vB, j + 5, 16);
            int   c6 = __shfl(cB, j + 6, 16); float v6 = __shfl(vB, j + 6, 16);
            int   c7 = __shfl(cB, j + 7, 16); float v7 = __shfl(vB, j + 7, 16);
            unsigned int u0 = y_u[(size_t)c0 * 16 + l];
            unsigned int u1 = y_u[(size_t)c1 * 16 + l];
            unsigned int u2 = y_u[(size_t)c2 * 16 + l];
            unsigned int u3 = y_u[(size_t)c3 * 16 + l];
            unsigned int u4 = y_u[(size_t)c4 * 16 + l];
            unsigned int u5 = y_u[(size_t)c5 * 16 + l];
            unsigned int u6 = y_u[(size_t)c6 * 16 + l];
            unsigned int u7 = y_u[(size_t)c7 * 16 + l];
            accL += bf_lo(u0) * v0; accH += bf_hi(u0) * v0;
            accL += bf_lo(u1) * v1; accH += bf_hi(u1) * v1;
            accL += bf_lo(u2) * v2; accH += bf_hi(u2) * v2;
            accL += bf_lo(u3) * v3; accH += bf_hi(u3) * v3;
            accL += bf_lo(u4) * v4; accH += bf_hi(u4) * v4;
            accL += bf_lo(u5) * v5; accH += bf_hi(u5) * v5;
            accL += bf_lo(u6) * v6; accH += bf_hi(u6) * v6;
            accL += bf_lo(u7) * v7; accH += bf_hi(u7) * v7;
        }
        if (j + 4 <= cnt) {
            int   c0 = __shfl(cB, j + 0, 16); float v0 = __shfl(vB, j + 0, 16);
            int   c1 = __shfl(cB, j + 1, 16); float v1 = __shfl(vB, j + 1, 16);
            int   c2 = __shfl(cB, j + 2, 16); float v2 = __shfl(vB, j + 2, 16);
            int   c3 = __shfl(cB, j + 3, 16); float v3 = __shfl(vB, j + 3, 16);
            unsigned int u0 = y_u[(size_t)c0 * 16 + l];
            unsigned int u1 = y_u[(size_t)c1 * 16 + l];
            unsigned int u2 = y_u[(size_t)c2 * 16 + l];
            unsigned int u3 = y_u[(size_t)c3 * 16 + l];
            accL += bf_lo(u0) * v0; accH += bf_hi(u0) * v0;
            accL += bf_lo(u1) * v1; accH += bf_hi(u1) * v1;
            accL += bf_lo(u2) * v2; accH += bf_hi(u2) * v2;
            accL += bf_lo(u3) * v3; accH += bf_hi(u3) * v3;
            j += 4;
        }
        if (j + 2 <= cnt) {
            int   c0 = __shfl(cB, j + 0, 16); float v0 = __shfl(vB, j + 0, 16);
            int   c1 = __shfl(cB, j + 1, 16); float v1 = __shfl(vB, j + 1, 16);
            unsigned int u0 = y_u[(size_t)c0 * 16 + l];
            unsigned int u1 = y_u[(size_t)c1 * 16 + l];
            accL += bf_lo(u0) * v0; accH += bf_hi(u0) * v0;
            accL += bf_lo(u1) * v1; accH += bf_hi(u1) * v1;
            j += 2;
        }
        if (j < cnt) {
            int   c0 = __shfl(cB, j, 16); float v0 = __shfl(vB, j, 16);
            unsigned int u0 = y_u[(size_t)c0 * 16 + l];
            accL += bf_lo(u0) * v0; accH += bf_hi(u0) * v0;
        }
    }
    out2[(size_t)n * 16 + l] = make_float2(accL, accH);
}

// ---------------------------------------------------------------------------
extern "C" void kernel_launch(void* const* d_in, const int* in_sizes, int n_in,
                              void* d_out, int out_size, void* d_ws, size_t ws_size,
                              hipStream_t stream) {
    const float* x    = (const float*)d_in[0];
    const int*   rows = (const int*)d_in[1];
    const int*   cols = (const int*)d_in[2];
    const float* vals = (const float*)d_in[3];
    const float* w    = (const float*)d_in[4];

    int n_nodes = in_sizes[0] / F;   // 100000
    int n_edges = in_sizes[1];       // 1600000

    // workspace: y_u [n_nodes*16 uints = 6.4 MB] | row_ptr [n_nodes+1 ints]
    unsigned int* y_u     = (unsigned int*)d_ws;
    int*          row_ptr = (int*)((char*)d_ws + (size_t)n_nodes * 16 * sizeof(unsigned int));

    int grid_xw = (n_nodes * F + 255) / 256;
    int grid_rp = (n_edges + 1 + 255) / 256;
    prep_kernel<<<grid_xw + grid_rp, 256, 0, stream>>>(x, w, y_u, rows, row_ptr,
                                                       n_nodes, n_edges, grid_xw);

    int grid_spmm = (n_nodes * 16 + 255) / 256;
    spmm_kernel<<<grid_spmm, 256, 0, stream>>>(y_u, cols, vals, row_ptr,
                                               (float2*)d_out, n_nodes);
}

// Round 4
// 51.138 us; speedup vs baseline: 2.3885x; 1.1558x over previous
//
#include <hip/hip_runtime.h>

#define F 32

// ---- bf16 helpers (manual, RNE) -------------------------------------------
__device__ __forceinline__ unsigned int f2bf_rne(float f) {
    unsigned int u = __float_as_uint(f);
    return (u + 0x7fffu + ((u >> 16) & 1u)) >> 16;          // bf16 bits in low 16
}
__device__ __forceinline__ float bf_lo(unsigned int u) {    // low bf16 -> f32
    return __uint_as_float(u << 16);
}
__device__ __forceinline__ float bf_hi(unsigned int u) {    // high bf16 -> f32
    return __uint_as_float(u & 0xffff0000u);
}

// ---------------------------------------------------------------------------
// Prep (fused).
// Blocks [0, grid_xw): y = x @ W, bf16-pair packed.
//   v4: lane = node. x row held in 32 VGPRs (8x float4). W indexed ONLY by
//   unroll-constant offsets from the uniform kernarg pointer -> compiler
//   scalarizes to s_load + SGPR-operand v_fma: 1 VALU op per MAC, no DS pipe.
//   (old version: 1 ds_bpermute + 1 ds_read + 1 fma per MAC ~ 20 us total.)
// Blocks [grid_xw, ...): CSR row_ptr from sorted COO rows.
// ---------------------------------------------------------------------------
__global__ void prep_kernel(const float* __restrict__ x, const float* __restrict__ w,
                            uint4* __restrict__ y_u4,
                            const int* __restrict__ rows, int* __restrict__ row_ptr,
                            int n_nodes, int n_edges, int grid_xw) {
    if ((int)blockIdx.x < grid_xw) {
        int n = blockIdx.x * blockDim.x + threadIdx.x;
        if (n >= n_nodes) return;

        const float4* xp = (const float4*)(x + (size_t)n * F);
        float xr[F];
#pragma unroll
        for (int j = 0; j < 8; ++j) {
            float4 t = xp[j];
            xr[4*j+0] = t.x; xr[4*j+1] = t.y; xr[4*j+2] = t.z; xr[4*j+3] = t.w;
        }
        float acc[F];
#pragma unroll
        for (int f = 0; f < F; ++f) acc[f] = 0.f;
#pragma unroll
        for (int k = 0; k < F; ++k) {
            float xk = xr[k];
#pragma unroll
            for (int f = 0; f < F; ++f)
                acc[f] = fmaf(xk, w[k * F + f], acc[f]);   // w: uniform -> s_load
        }
        uint4 o[4];
        unsigned int* op = (unsigned int*)o;
#pragma unroll
        for (int k = 0; k < 16; ++k)
            op[k] = f2bf_rne(acc[2*k]) | (f2bf_rne(acc[2*k+1]) << 16);
#pragma unroll
        for (int j = 0; j < 4; ++j) y_u4[(size_t)n * 4 + j] = o[j];
    } else {
        int e = (blockIdx.x - grid_xw) * blockDim.x + threadIdx.x;
        if (e > n_edges) return;
        int prev = (e == 0) ? -1 : rows[e - 1];
        int cur  = (e == n_edges) ? n_nodes : rows[e];
        for (int r = prev + 1; r <= cur; ++r) row_ptr[r] = e;
    }
}

// ---------------------------------------------------------------------------
// SpMM: one 16-lane group per node; lane l owns feature pair (2l, 2l+1).
// v4: metadata via DIRECT group-uniform VMEM loads (L1 broadcast) instead of
// coalesced-batch + __shfl: the 2 ds_bpermute per edge were ~6 cy DS-pipe
// issue each (~20 us aggregate). 8-deep unrolled gathers for MLP; OOB edges
// clamp to e0 (its line is fetched by j=0 anyway -> no extra traffic, val=0).
// ---------------------------------------------------------------------------
__global__ void spmm_kernel(const unsigned int* __restrict__ y_u,
                            const int* __restrict__ cols,
                            const float* __restrict__ vals,
                            const int* __restrict__ row_ptr,
                            float2* __restrict__ out2, int n_nodes) {
    int gid = blockIdx.x * blockDim.x + threadIdx.x;
    int n = gid >> 4;
    int l = gid & 15;
    if (n >= n_nodes) return;

    int e0 = row_ptr[n];
    int e1 = row_ptr[n + 1];
    float accL = 0.f, accH = 0.f;

    for (int base = e0; base < e1; base += 8) {
        int   c[8];
        float v[8];
#pragma unroll
        for (int j = 0; j < 8; ++j) {
            int idx = base + j;
            bool ok = idx < e1;
            int idx2 = ok ? idx : e0;          // always a valid edge of this row
            c[j] = cols[idx2];                 // uniform within group -> L1 broadcast
            v[j] = ok ? vals[idx2] : 0.f;
        }
        unsigned int u[8];
#pragma unroll
        for (int j = 0; j < 8; ++j)
            u[j] = y_u[(size_t)c[j] * 16 + l]; // 8 independent 64B-row gathers
#pragma unroll
        for (int j = 0; j < 8; ++j) {
            accL += bf_lo(u[j]) * v[j];
            accH += bf_hi(u[j]) * v[j];
        }
    }
    out2[(size_t)n * 16 + l] = make_float2(accL, accH);
}

// ---------------------------------------------------------------------------
extern "C" void kernel_launch(void* const* d_in, const int* in_sizes, int n_in,
                              void* d_out, int out_size, void* d_ws, size_t ws_size,
                              hipStream_t stream) {
    const float* x    = (const float*)d_in[0];
    const int*   rows = (const int*)d_in[1];
    const int*   cols = (const int*)d_in[2];
    const float* vals = (const float*)d_in[3];
    const float* w    = (const float*)d_in[4];

    int n_nodes = in_sizes[0] / F;   // 100000
    int n_edges = in_sizes[1];       // 1600000

    // workspace: y_u [n_nodes*16 uints = 6.4 MB] | row_ptr [n_nodes+1 ints]
    unsigned int* y_u     = (unsigned int*)d_ws;
    int*          row_ptr = (int*)((char*)d_ws + (size_t)n_nodes * 16 * sizeof(unsigned int));

    int grid_xw = (n_nodes + 255) / 256;                 // lane = node now
    int grid_rp = (n_edges + 1 + 255) / 256;
    prep_kernel<<<grid_xw + grid_rp, 256, 0, stream>>>(x, w, (uint4*)y_u, rows, row_ptr,
                                                       n_nodes, n_edges, grid_xw);

    int grid_spmm = (n_nodes * 16 + 255) / 256;
    spmm_kernel<<<grid_spmm, 256, 0, stream>>>(y_u, cols, vals, row_ptr,
                                               (float2*)d_out, n_nodes);
}